// Round 11
// baseline (743.355 us; speedup 1.0000x reference)
//
#include <hip/hip_runtime.h>
#include <cstdint>

typedef __bf16 bf16x8 __attribute__((ext_vector_type(8)));
typedef float f32x4 __attribute__((ext_vector_type(4)));
typedef unsigned short u16;

#define GBAR() asm volatile("s_barrier" ::: "memory")
#define SBAR0() __builtin_amdgcn_sched_barrier(0)
#define LGKM0() do { asm volatile("s_waitcnt lgkmcnt(0)" ::: "memory"); SBAR0(); } while (0)
#define VM8()  asm volatile("s_waitcnt vmcnt(8)" ::: "memory")
#define MFMA16(a, b, c) __builtin_amdgcn_mfma_f32_16x16x32_bf16((a), (b), (c), 0, 0, 0)

__device__ __forceinline__ u16 f2bf(float f) {
  unsigned u = __builtin_bit_cast(unsigned, f);
  u += 0x7fffu + ((u >> 16) & 1u);   // RNE, matches numpy/jax bf16 cast
  return (u16)(u >> 16);
}
__device__ __forceinline__ float bfu(ushort4 v, int r) {
  unsigned short s = (r == 0) ? v.x : (r == 1) ? v.y : (r == 2) ? v.z : v.w;
  return __builtin_bit_cast(float, (unsigned)s << 16);
}

// ---------------- cast f32 -> bf16 (x only) ----------------------------------
__global__ void cast_f32_bf16(const float* __restrict__ in, u16* __restrict__ out,
                              int n4) {
  int i = blockIdx.x * blockDim.x + threadIdx.x;
  int stride = gridDim.x * blockDim.x;
  for (; i < n4; i += stride) {
    float4 v = ((const float4*)in)[i];
    ushort4 o;
    o.x = f2bf(v.x); o.y = f2bf(v.y); o.z = f2bf(v.z); o.w = f2bf(v.w);
    ((ushort4*)out)[i] = o;
  }
}

// ------------- batched transpose+cast of the 3 weight matrices ---------------
__global__ void transpose_all(const float* __restrict__ Wa, const float* __restrict__ Wm,
                              const float* __restrict__ Wp,
                              u16* __restrict__ oa, u16* __restrict__ om,
                              u16* __restrict__ op) {
  __shared__ float t[64][65];
  int z = blockIdx.z;
  const float* in = (z == 0) ? Wa : (z == 1) ? Wm : Wp;
  u16* out = (z == 0) ? oa : (z == 1) ? om : op;
  int C = (z == 0) ? 2048 : 1024;
  const int R = 1024;
  if (blockIdx.x * 64 >= C) return;
  int tc = blockIdx.x * 64, tr = blockIdx.y * 64;
  int c = threadIdx.x & 63, r0 = threadIdx.x >> 6;
  #pragma unroll
  for (int p = 0; p < 16; ++p) {
    int r = p * 4 + r0;
    t[r][c] = in[(long)(tr + r) * C + (tc + c)];
  }
  __syncthreads();
  #pragma unroll
  for (int p = 0; p < 16; ++p) {
    int r = p * 4 + r0;
    out[(long)(tc + r) * R + (tr + c)] = f2bf(t[c][r]);
  }
}

// ------- mask prep: in [49][4096] f32 -> out [4096][64] bf16 (q zero-pad) ----
__global__ void mask_prep(const float* __restrict__ in, u16* __restrict__ out) {
  __shared__ float t[64][65];
  int s0 = blockIdx.x * 64;
  int c = threadIdx.x & 63, r0 = threadIdx.x >> 6;
  #pragma unroll
  for (int p = 0; p < 16; ++p) {
    int q = p * 4 + r0;
    t[q][c] = (q < 49) ? in[(long)q * 4096 + s0 + c] : 0.f;
  }
  __syncthreads();
  #pragma unroll
  for (int p = 0; p < 16; ++p) {
    int r = p * 4 + r0;
    out[(long)(s0 + r) * 64 + c] = f2bf(t[c][r]);
  }
}

// =============== 256x256x(K=1024) bf16 GEMM, weights-direct ==================
// 8 waves (2M x 4N), BK=64. Only the x-operand is LDS-staged (3 x 32KB bufs);
// the weight operand (2MB, L2-resident) is loaded straight into VGPR frags
// each K-tile (16-lane row-gather, 16B/lane). LDS traffic/K-tile/CU drops
// 256KB->160KB; 1 barrier + 2 lgkm0 per K-tile; NO manual vmcnt in the loop:
// correctness ledger: compiler's oldest-first vmcnt wait for the weight frags
// in body t-1 transitively drains STAGE(t) (issued earlier, end of body t-2);
// cross-wave via body t-1's barrier. Restage target = the buffer last read in
// body t-1 (all waves past that barrier). Prologue: explicit vmcnt(4).
// MODE 0: x = A (af from LDS), W_k = B direct. out K[b][h][s][d], bias[col].
// MODE 1: x = B (bn from LDS), W_v = A direct (lo/hi halves). out Vt, bias row.
template<int MODE>
__global__ __launch_bounds__(512, 2) void gemm256(
    const u16* __restrict__ A, const u16* __restrict__ BT,
    const float* __restrict__ bias, void* __restrict__ outp)
{
  __shared__ __align__(16) char lds[98304];   // 3 x 32KB x-tile buffers

  int tid = threadIdx.x;
  int l = tid & 63, w = tid >> 6;
  int wr = w >> 2, wc = w & 3;
  int lr = l & 15, lh = l >> 4;

  int bid = blockIdx.x;
  int mt, nt;
  long out_off = 0;
  const u16* Ap = A;
  const u16* BTp = BT;
  if constexpr (MODE == 0) {
    int wg = (bid & 7) * 128 + (bid >> 3);   // XCD-contiguous (1024 % 8 == 0)
    mt = wg >> 2; nt = wg & 3;
  } else {
    int wg = (bid & 7) * 8 + (bid >> 3);     // 64 blocks per batch
    mt = wg & 3; nt = wg >> 2;
    int b = blockIdx.y;
    BTp = BT + (long)b * 4194304;
    out_off = (long)b * 4194304;
  }
  long Arow0 = (long)mt * 256;
  long Brow0 = (long)nt * 256;

  // ---- x staging (both modes): 256 rows x 64 cols per K-tile ---------------
  const u16* xbase = (MODE == 0) ? Ap : BTp;
  long xrow0 = (MODE == 0) ? Arow0 : Brow0;
  int rho = (w << 3) + (l >> 3);                 // 0..63
  int csw = ((l & 7) ^ (l >> 3)) << 3;           // pre-swizzled source chunk
  const u16* xg = xbase + (xrow0 + rho) * 1024 + csw;
  char* ldsthr = lds + rho * 128 + (l & 7) * 16; // linear dest, chunk = l&7

  auto STAGE_X = [&](int bi, int st) {
    char* d = ldsthr + bi * 32768;
    const u16* s = xg + (long)st * 64;
    #pragma unroll
    for (int q = 0; q < 4; ++q)                  // rows rho + {0,64,128,192}
      __builtin_amdgcn_global_load_lds(
          (const __attribute__((address_space(1))) void*)(s + (long)q * 65536),
          (__attribute__((address_space(3))) void*)(d + q * 8192), 16, 0, 0);
  };

  // ---- weight direct-load base (per-lane row gather) ------------------------
  const u16* wgp = (MODE == 0)
      ? BTp + (Brow0 + wc * 64 + lr) * 1024 + lh * 8
      : Ap  + (Arow0 + wr * 128 + lr) * 1024 + lh * 8;

  int arow_b = (wr * 128 + lr) * 128;            // MODE 0 x-frag rows
  int brow_b = (wc * 64 + lr) * 128;             // MODE 1 x-frag rows
  int xr0 = (lh ^ (lr & 7)) << 4;
  int xr1 = ((4 + lh) ^ (lr & 7)) << 4;

  f32x4 acc[8][4];
  #pragma unroll
  for (int m = 0; m < 8; ++m)
    #pragma unroll
    for (int n = 0; n < 4; ++n) acc[m][n] = f32x4{0.f, 0.f, 0.f, 0.f};

  bf16x8 af[4][2], bn0[2][2], bn1[2][2];

  auto Q = [&](int mo, int no, bf16x8 (&bn)[2][2]) {   // 16 MFMA quadrant
    __builtin_amdgcn_s_setprio(1);
    #pragma unroll
    for (int m = 0; m < 4; ++m)
      #pragma unroll
      for (int n = 0; n < 2; ++n) {
        acc[mo + m][no + n] = MFMA16(af[m][0], bn[n][0], acc[mo + m][no + n]);
        acc[mo + m][no + n] = MFMA16(af[m][1], bn[n][1], acc[mo + m][no + n]);
      }
    __builtin_amdgcn_s_setprio(0);
  };

  // ---- prologue: buffers 0,1; drain buffer 0 --------------------------------
  STAGE_X(0, 0);
  STAGE_X(1, 1);
  asm volatile("s_waitcnt vmcnt(4)" ::: "memory");   // STAGE(0) landed
  GBAR();

  int cur = 0;
  for (int t = 0; t < 16; ++t) {
    int buf = cur * 32768;
    if constexpr (MODE == 0) {
      // weight B-frags direct (8 loads); compiler auto-waits before Q
      #pragma unroll
      for (int n = 0; n < 2; ++n)
        #pragma unroll
        for (int h = 0; h < 2; ++h) {
          bn0[n][h] = *(const bf16x8*)(wgp + n * 16384 + t * 64 + h * 32);
          bn1[n][h] = *(const bf16x8*)(wgp + (n + 2) * 16384 + t * 64 + h * 32);
        }
      SBAR0();
      #pragma unroll
      for (int m = 0; m < 4; ++m) {                      // x-frags lo
        af[m][0] = *(const bf16x8*)(lds + buf + arow_b + m * 2048 + xr0);
        af[m][1] = *(const bf16x8*)(lds + buf + arow_b + m * 2048 + xr1);
      }
      LGKM0();
      Q(0, 0, bn0); Q(0, 2, bn1);
      #pragma unroll
      for (int m = 0; m < 4; ++m) {                      // x-frags hi (WAR)
        af[m][0] = *(const bf16x8*)(lds + buf + arow_b + 8192 + m * 2048 + xr0);
        af[m][1] = *(const bf16x8*)(lds + buf + arow_b + 8192 + m * 2048 + xr1);
      }
      LGKM0();
      Q(4, 0, bn0); Q(4, 2, bn1);
    } else {
      // weight A-frags lo direct (8 loads)
      #pragma unroll
      for (int m = 0; m < 4; ++m)
        #pragma unroll
        for (int h = 0; h < 2; ++h)
          af[m][h] = *(const bf16x8*)(wgp + m * 16384 + t * 64 + h * 32);
      SBAR0();
      #pragma unroll
      for (int n = 0; n < 2; ++n) {                      // x-frags from LDS
        bn0[n][0] = *(const bf16x8*)(lds + buf + brow_b + n * 2048 + xr0);
        bn0[n][1] = *(const bf16x8*)(lds + buf + brow_b + n * 2048 + xr1);
        bn1[n][0] = *(const bf16x8*)(lds + buf + brow_b + 4096 + n * 2048 + xr0);
        bn1[n][1] = *(const bf16x8*)(lds + buf + brow_b + 4096 + n * 2048 + xr1);
      }
      LGKM0();
      Q(0, 0, bn0); Q(0, 2, bn1);
      #pragma unroll
      for (int m = 0; m < 4; ++m)                        // weight A-frags hi
        #pragma unroll
        for (int h = 0; h < 2; ++h)
          af[m][h] = *(const bf16x8*)(wgp + 65536 + m * 16384 + t * 64 + h * 32);
      Q(4, 0, bn0); Q(4, 2, bn1);                        // auto vmcnt wait
    }
    GBAR();   // all waves done reading buf(t); restage target safe
    {
      int st = t + 2;
      int bs = cur + 2; if (bs >= 3) bs -= 3;
      STAGE_X(bs, st < 16 ? st : 15);                    // tail stages benign
    }
    ++cur; if (cur == 3) cur = 0;
  }

  asm volatile("s_waitcnt vmcnt(0) lgkmcnt(0)" ::: "memory");

  // ---- epilogue (unchanged) --------------------------------------------------
  #pragma unroll
  for (int m = 0; m < 8; ++m) {
    #pragma unroll
    for (int n = 0; n < 4; ++n) {
      #pragma unroll
      for (int r = 0; r < 4; ++r) {
        long row = Arow0 + wr * 128 + m * 16 + lh * 4 + r;
        long col = Brow0 + wc * 64 + n * 16 + lr;
        float v = acc[m][n][r];
        if constexpr (MODE == 0) {
          v += bias[col];
          long addr = (row >> 12) * 4194304 + (col >> 6) * 262144
                    + (row & 4095) * 64 + (col & 63);
          ((u16*)outp)[addr] = f2bf(v);
        } else {
          v += bias[1024 + row];
          ((u16*)outp)[out_off + row * 4096 + col] = f2bf(v);
        }
      }
    }
  }
}

// ---------------- 64x64x(K=1024) GEMM for the small matmuls ------------------
template<int MODE>
__global__ __launch_bounds__(256, 4) void gemm64(
    const void* __restrict__ Ap, const u16* __restrict__ BT,
    const float* __restrict__ bias, void* __restrict__ outp)
{
  __shared__ u16 As[64][64];
  __shared__ u16 Bs[64][64];

  int bid = blockIdx.x;
  int mt = bid >> 4, nt = bid & 15;
  int tid = threadIdx.x;
  int l = tid & 63, w = tid >> 6;
  int wr = w >> 1, wc = w & 1;
  int lr = l & 15, lh = l >> 4;

  f32x4 acc[2][2];
  #pragma unroll
  for (int m = 0; m < 2; ++m)
    #pragma unroll
    for (int n = 0; n < 2; ++n) acc[m][n] = f32x4{0.f, 0.f, 0.f, 0.f};

  long arow0 = (long)mt * 64;
  long brow0 = (long)nt * 64;
  int srow = tid >> 3, sc = tid & 7;

  for (int kt = 0; kt < 16; ++kt) {
    int ko = kt * 64;
    #pragma unroll
    for (int p = 0; p < 2; ++p) {
      int row = srow + p * 32;
      int cs = (sc ^ (row & 7)) << 3;
      __builtin_amdgcn_global_load_lds(
          (const __attribute__((address_space(1))) void*)(BT + (brow0 + row) * 1024 + ko + cs),
          (__attribute__((address_space(3))) void*)(&Bs[row][sc * 8]), 16, 0, 0);
      if constexpr (MODE == 3)
        __builtin_amdgcn_global_load_lds(
            (const __attribute__((address_space(1))) void*)((const u16*)Ap + (arow0 + row) * 1024 + ko + cs),
            (__attribute__((address_space(3))) void*)(&As[row][sc * 8]), 16, 0, 0);
    }
    if constexpr (MODE == 2) {
      #pragma unroll
      for (int p = 0; p < 2; ++p) {
        int row = srow + p * 32;
        int cs = (sc ^ (row & 7)) << 3;   // SOURCE chunk (pre-swizzled)
        ushort4 o0 = {0, 0, 0, 0}, o1 = {0, 0, 0, 0};
        if (arow0 + row < 784) {
          const float* src = (const float*)Ap + (arow0 + row) * 1024 + ko + cs;
          float4 f0 = *(const float4*)src;
          float4 f1 = *(const float4*)(src + 4);
          o0.x = f2bf(f0.x); o0.y = f2bf(f0.y); o0.z = f2bf(f0.z); o0.w = f2bf(f0.w);
          o1.x = f2bf(f1.x); o1.y = f2bf(f1.y); o1.z = f2bf(f1.z); o1.w = f2bf(f1.w);
        }
        *(ushort4*)(&As[row][sc * 8]) = o0;       // DEST chunk sc
        *(ushort4*)(&As[row][sc * 8 + 4]) = o1;
      }
    }
    __syncthreads();
    #pragma unroll
    for (int kk = 0; kk < 2; ++kk) {
      bf16x8 afr[2], bfr[2];
      #pragma unroll
      for (int m = 0; m < 2; ++m) {
        int row = wr * 32 + m * 16 + lr;
        afr[m] = *(const bf16x8*)((const char*)&As[row][0] + (((kk * 4 + lh) ^ (row & 7)) << 4));
      }
      #pragma unroll
      for (int n = 0; n < 2; ++n) {
        int row = wc * 32 + n * 16 + lr;
        bfr[n] = *(const bf16x8*)((const char*)&Bs[row][0] + (((kk * 4 + lh) ^ (row & 7)) << 4));
      }
      #pragma unroll
      for (int m = 0; m < 2; ++m)
        #pragma unroll
        for (int n = 0; n < 2; ++n)
          acc[m][n] = MFMA16(afr[m], bfr[n], acc[m][n]);
    }
    __syncthreads();
  }

  #pragma unroll
  for (int m = 0; m < 2; ++m) {
    #pragma unroll
    for (int n = 0; n < 2; ++n) {
      #pragma unroll
      for (int r = 0; r < 4; ++r) {
        int row = (int)arow0 + wr * 32 + m * 16 + lh * 4 + r;
        int col = (int)brow0 + wc * 32 + n * 16 + lr;
        if (row < 784) {
          float v = acc[m][n][r] + bias[col];
          if constexpr (MODE == 2) {
            int b = row / 49, qi = row - b * 49;
            long addr = ((long)(b * 16 + (col >> 6)) * 64 + qi) * 64 + (col & 63);
            ((u16*)outp)[addr] = f2bf(v);
          } else {
            ((float*)outp)[(long)row * 1024 + col] = v;
          }
        }
      }
    }
  }
}

// ---------------- fused attention partials: LDS-staged streaming -------------
__global__ __launch_bounds__(256, 4) void attn_part(
    const u16* __restrict__ Kt, const u16* __restrict__ Vt, const u16* __restrict__ Q,
    const u16* __restrict__ maskT,
    float* __restrict__ partA, float* __restrict__ prs)
{
  __shared__ __align__(16) char lds[40960];

  int bh = blockIdx.x, chunk = blockIdx.y;
  int tid = threadIdx.x;
  int l = tid & 63, w = tid >> 6;
  int lr = l & 15, lh = l >> 4;

  const u16* Kb = Kt + (long)bh * 262144;
  const u16* Vb = Vt + (long)bh * 262144;
  const u16* Qb = Q + (long)bh * 4096;

  int t0 = chunk * 16;
  const int nt = 16;
  int tmax = t0 + nt - 1;

  int strow = tid >> 3;
  int sc = tid & 7;

  auto STAGE = [&](int buf, int tt) {
    long s0 = (long)tt * 64;
    #pragma unroll
    for (int h = 0; h < 2; ++h) {
      int row = h * 32 + strow;
      int cs = (sc ^ (row & 7)) << 3;
      const u16* ksrc = Kb + (s0 + row) * 64 + cs;
      char* kdst = lds + buf * 8192 + row * 128 + sc * 16;
      __builtin_amdgcn_global_load_lds(
          (const __attribute__((address_space(1))) void*)ksrc,
          (__attribute__((address_space(3))) void*)kdst, 16, 0, 0);
      const u16* vsrc = Vb + (long)row * 4096 + s0 + cs;
      char* vdst = lds + 16384 + buf * 8192 + row * 128 + sc * 16;
      __builtin_amdgcn_global_load_lds(
          (const __attribute__((address_space(1))) void*)vsrc,
          (__attribute__((address_space(3))) void*)vdst, 16, 0, 0);
    }
  };

  bf16x8 qf[2];
  #pragma unroll
  for (int kf2 = 0; kf2 < 2; ++kf2)
    qf[kf2] = *(const bf16x8*)(Qb + (w * 16 + lr) * 64 + kf2 * 32 + lh * 8);

  bf16x8 ones;
  #pragma unroll
  for (int j = 0; j < 8; ++j) ones[j] = (__bf16)1.0f;

  f32x4 acc_a[4];
  #pragma unroll
  for (int n = 0; n < 4; ++n) acc_a[n] = f32x4{0.f, 0.f, 0.f, 0.f};
  f32x4 acc_rs = f32x4{0.f, 0.f, 0.f, 0.f};

  char* Pw = lds + 32768 + w * 2048;
  const u16* mbase = maskT + w * 16 + lh * 4;

  STAGE(0, t0);
  STAGE(1, t0 + 1);
  ushort4 mvu[4];
  #pragma unroll
  for (int sf = 0; sf < 4; ++sf)
    mvu[sf] = *(const ushort4*)(mbase + ((long)t0 * 64 + sf * 16 + lr) * 64);
  VM8();
  GBAR();

  for (int it = 0; it < nt; ++it) {
    int buf = it & 1;
    const char* Kl = lds + buf * 8192;
    const char* Vl = lds + 16384 + buf * 8192;

    int tn = it + 1 < nt ? t0 + it + 1 : tmax;
    ushort4 mvn[4];
    #pragma unroll
    for (int sf = 0; sf < 4; ++sf)
      mvn[sf] = *(const ushort4*)(mbase + ((long)tn * 64 + sf * 16 + lr) * 64);

    bf16x8 kf[4][2];
    #pragma unroll
    for (int sf = 0; sf < 4; ++sf) {
      int srw = sf * 16 + lr;
      int xb = srw & 7;
      kf[sf][0] = *(const bf16x8*)(Kl + srw * 128 + ((lh ^ xb) << 4));
      kf[sf][1] = *(const bf16x8*)(Kl + srw * 128 + (((4 + lh) ^ xb) << 4));
    }
    f32x4 lg[4];
    #pragma unroll
    for (int sf = 0; sf < 4; ++sf) {
      f32x4 t = f32x4{0.f, 0.f, 0.f, 0.f};
      t = MFMA16(qf[0], kf[sf][0], t);
      t = MFMA16(qf[1], kf[sf][1], t);
      lg[sf] = t;
    }

    bf16x8 vf[2][4];
    #pragma unroll
    for (int k2 = 0; k2 < 2; ++k2)
      #pragma unroll
      for (int n = 0; n < 4; ++n) {
        int vrow = n * 16 + lr;
        vf[k2][n] = *(const bf16x8*)(Vl + vrow * 128 + (((k2 * 4 + lh) ^ (lr & 7)) << 4));
      }

    #pragma unroll
    for (int sf = 0; sf < 4; ++sf) {
      #pragma unroll
      for (int r = 0; r < 4; ++r) {
        int qq = lh * 4 + r;
        float e = __expf(lg[sf][r] * 0.125f) * bfu(mvu[sf], r);
        int byte = (qq * 128 + (sf * 16 + lr) * 2) ^ ((qq & 7) << 4);
        *(u16*)(Pw + byte) = f2bf(e);
      }
    }

    #pragma unroll
    for (int k2 = 0; k2 < 2; ++k2) {
      int byte = (lr * 128 + k2 * 64 + lh * 16) ^ ((lr & 7) << 4);
      bf16x8 pf;
      __builtin_memcpy(&pf, Pw + byte, 16);
      #pragma unroll
      for (int n = 0; n < 4; ++n)
        acc_a[n] = MFMA16(pf, vf[k2][n], acc_a[n]);
      acc_rs = MFMA16(pf, ones, acc_rs);
    }

    LGKM0();
    GBAR();
    { int tt = it + 2 < nt ? t0 + it + 2 : tmax; STAGE(buf, tt); }
    VM8();
    GBAR();

    #pragma unroll
    for (int sf = 0; sf < 4; ++sf) mvu[sf] = mvn[sf];
  }

  long base = ((long)bh * 4 + chunk) * 64;
  #pragma unroll
  for (int r = 0; r < 4; ++r) {
    int q = w * 16 + lh * 4 + r;
    if (lr == 0) prs[base + q] = acc_rs[r];
    #pragma unroll
    for (int n = 0; n < 4; ++n)
      partA[(base + q) * 64 + n * 16 + lr] = acc_a[n][r];
  }
}

// ---------------- reduce 4 s-chunk partials, normalize, write a_bf -----------
__global__ __launch_bounds__(256) void attn_reduce(
    const float* __restrict__ partA, const float* __restrict__ prs,
    u16* __restrict__ Abf)
{
  int bh = blockIdx.x;
  int t = threadIdx.x;
  int q = t >> 2, d0 = (t & 3) * 16;
  if (q >= 49) return;
  int b = bh >> 4, h = bh & 15;

  float rs = 1e-6f;
  #pragma unroll
  for (int c = 0; c < 4; ++c) rs += prs[((long)bh * 4 + c) * 64 + q];

  #pragma unroll
  for (int j = 0; j < 4; ++j) {
    float4 s = float4{0.f, 0.f, 0.f, 0.f};
    #pragma unroll
    for (int c = 0; c < 4; ++c) {
      float4 v = *(const float4*)(partA + (((long)bh * 4 + c) * 64 + q) * 64 + d0 + j * 4);
      s.x += v.x; s.y += v.y; s.z += v.z; s.w += v.w;
    }
    ushort4 o;
    o.x = f2bf(s.x / rs); o.y = f2bf(s.y / rs);
    o.z = f2bf(s.z / rs); o.w = f2bf(s.w / rs);
    *(ushort4*)(Abf + ((long)(b * 49 + q) * 1024 + h * 64 + d0 + j * 4)) = o;
  }
}

// -----------------------------------------------------------------------------
extern "C" void kernel_launch(void* const* d_in, const int* in_sizes, int n_in,
                              void* d_out, int out_size, void* d_ws, size_t ws_size,
                              hipStream_t stream) {
  const float* x      = (const float*)d_in[0];
  const float* y      = (const float*)d_in[1];
  const float* mask   = (const float*)d_in[2];
  const float* W_attn = (const float*)d_in[3];
  const float* b_attn = (const float*)d_in[4];
  const float* W_mlp  = (const float*)d_in[5];
  const float* b_mlp  = (const float*)d_in[6];
  const float* W_proj = (const float*)d_in[7];
  const float* b_proj = (const float*)d_in[8];

  if (ws_size < 417333248ULL) return;

  char* ws = (char*)d_ws;
  u16* x_bf    = (u16*)(ws);                   // 128 MB  [65536][1024]
  u16* Kt      = (u16*)(ws + 134217728L);      // 128 MB  [b][h][s][d]
  u16* Vt      = (u16*)(ws + 268435456L);      // 128 MB  [b][h][d][s]
  u16* WT_attn = (u16*)(ws + 402653184L);      // 4 MB    [2048][1024]
  u16* WT_mlp  = (u16*)(ws + 406847488L);      // 2 MB
  u16* WT_proj = (u16*)(ws + 408944640L);      // 2 MB
  u16* q_ws    = (u16*)(ws + 412876800L);      // 2 MB    [b][h][64][64]
  u16* a_bf    = (u16*)(ws + 414973952L);      // 1.75 MB [896][1024]
  u16* maskT   = (u16*)(ws + 416808960L);      // 512 KB  [4096][64] bf16
  float* partA = (float*)(ws);                 // 16 MB   (reuses x_bf region)
  float* prs   = (float*)(ws + 16777216L);     // 256 KB

  cast_f32_bf16<<<2048, 256, 0, stream>>>(x, x_bf, 16777216);
  transpose_all<<<dim3(32, 16, 3), 256, 0, stream>>>(W_attn, W_mlp, W_proj,
                                                     WT_attn, WT_mlp, WT_proj);
  mask_prep<<<64, 256, 0, stream>>>(mask, maskT);

  gemm256<0><<<1024, 512, 0, stream>>>(x_bf, WT_attn, b_attn, Kt);
  gemm256<1><<<dim3(64, 16), 512, 0, stream>>>(WT_attn + 1048576, x_bf, b_attn, Vt);
  gemm64<2><<<224, 256, 0, stream>>>(y, WT_mlp, b_mlp, q_ws);

  attn_part<<<dim3(256, 4), 256, 0, stream>>>(Kt, Vt, q_ws, maskT, partA, prs);
  attn_reduce<<<256, 256, 0, stream>>>(partA, prs, a_bf);

  gemm64<3><<<224, 256, 0, stream>>>(a_bf, WT_proj, b_proj, d_out);
}

// Round 12
// 555.485 us; speedup vs baseline: 1.3382x; 1.3382x over previous
//
#include <hip/hip_runtime.h>
#include <cstdint>

typedef __bf16 bf16x8 __attribute__((ext_vector_type(8)));
typedef float f32x4 __attribute__((ext_vector_type(4)));
typedef unsigned short u16;

#define GBAR() asm volatile("s_barrier" ::: "memory")
#define SBAR0() __builtin_amdgcn_sched_barrier(0)
#define LGKM0() do { asm volatile("s_waitcnt lgkmcnt(0)" ::: "memory"); SBAR0(); } while (0)
#define VM6()  asm volatile("s_waitcnt vmcnt(6)" ::: "memory")
#define VM8()  asm volatile("s_waitcnt vmcnt(8)" ::: "memory")
#define MFMA16(a, b, c) __builtin_amdgcn_mfma_f32_16x16x32_bf16((a), (b), (c), 0, 0, 0)

__device__ __forceinline__ u16 f2bf(float f) {
  unsigned u = __builtin_bit_cast(unsigned, f);
  u += 0x7fffu + ((u >> 16) & 1u);   // RNE, matches numpy/jax bf16 cast
  return (u16)(u >> 16);
}
__device__ __forceinline__ float bfu(ushort4 v, int r) {
  unsigned short s = (r == 0) ? v.x : (r == 1) ? v.y : (r == 2) ? v.z : v.w;
  return __builtin_bit_cast(float, (unsigned)s << 16);
}

// ---------------- cast f32 -> bf16 (x only) ----------------------------------
__global__ void cast_f32_bf16(const float* __restrict__ in, u16* __restrict__ out,
                              int n4) {
  int i = blockIdx.x * blockDim.x + threadIdx.x;
  int stride = gridDim.x * blockDim.x;
  for (; i < n4; i += stride) {
    float4 v = ((const float4*)in)[i];
    ushort4 o;
    o.x = f2bf(v.x); o.y = f2bf(v.y); o.z = f2bf(v.z); o.w = f2bf(v.w);
    ((ushort4*)out)[i] = o;
  }
}

// ------------- batched transpose+cast of the 3 weight matrices ---------------
__global__ void transpose_all(const float* __restrict__ Wa, const float* __restrict__ Wm,
                              const float* __restrict__ Wp,
                              u16* __restrict__ oa, u16* __restrict__ om,
                              u16* __restrict__ op) {
  __shared__ float t[64][65];
  int z = blockIdx.z;
  const float* in = (z == 0) ? Wa : (z == 1) ? Wm : Wp;
  u16* out = (z == 0) ? oa : (z == 1) ? om : op;
  int C = (z == 0) ? 2048 : 1024;
  const int R = 1024;
  if (blockIdx.x * 64 >= C) return;
  int tc = blockIdx.x * 64, tr = blockIdx.y * 64;
  int c = threadIdx.x & 63, r0 = threadIdx.x >> 6;
  #pragma unroll
  for (int p = 0; p < 16; ++p) {
    int r = p * 4 + r0;
    t[r][c] = in[(long)(tr + r) * C + (tc + c)];
  }
  __syncthreads();
  #pragma unroll
  for (int p = 0; p < 16; ++p) {
    int r = p * 4 + r0;
    out[(long)(tc + r) * R + (tr + c)] = f2bf(t[c][r]);
  }
}

// ------- mask prep: in [49][4096] f32 -> out [4096][64] bf16 (q zero-pad) ----
__global__ void mask_prep(const float* __restrict__ in, u16* __restrict__ out) {
  __shared__ float t[64][65];
  int s0 = blockIdx.x * 64;
  int c = threadIdx.x & 63, r0 = threadIdx.x >> 6;
  #pragma unroll
  for (int p = 0; p < 16; ++p) {
    int q = p * 4 + r0;
    t[q][c] = (q < 49) ? in[(long)q * 4096 + s0 + c] : 0.f;
  }
  __syncthreads();
  #pragma unroll
  for (int p = 0; p < 16; ++p) {
    int r = p * 4 + r0;
    out[(long)(s0 + r) * 64 + c] = f2bf(t[c][r]);
  }
}

// =============== 256x256x(K=1024) bf16 GEMM, m201 8-phase, merged KV =========
// Round-10 kernel (proven 465us config) with BOTH modes in one launch:
// blockIdx.y == 0 -> K-mode (A = x, BT = W_k^T rows 0..1023, out Kt),
// blockIdx.y == 1 -> V-mode (A = W_v^T, BT = x_b per batch, out Vt transposed).
// Modes write disjoint outputs and share read-only inputs, so V-mode wgs
// backfill CUs idled by K-mode's ragged tail (1 wg/CU, 4 rounds each).
__global__ __launch_bounds__(512, 2) void gemm256kv(
    const u16* __restrict__ x, const u16* __restrict__ wt,
    const float* __restrict__ bias, u16* __restrict__ Kt, u16* __restrict__ Vt)
{
  __shared__ __align__(16) char lds[131072];  // [2 buf][A 32K | B 32K]

  int tid = threadIdx.x;
  int l = tid & 63, w = tid >> 6;
  int wr = w >> 2, wc = w & 3;
  int lr = l & 15, lh = l >> 4;

  int bid = blockIdx.x;
  bool isK = (blockIdx.y == 0);
  int mt, nt;
  long out_off = 0;
  const u16* Ap;
  const u16* BTp;
  if (isK) {
    int wg = (bid & 7) * 128 + (bid >> 3);   // XCD-contiguous (1024 % 8 == 0)
    mt = wg >> 2; nt = wg & 3;
    Ap = x; BTp = wt;
  } else {
    int b = bid >> 6, sub = bid & 63;
    int wg = (sub & 7) * 8 + (sub >> 3);     // 64 blocks per batch
    mt = wg & 3; nt = wg >> 2;
    Ap = wt + 1048576;                        // V-half of W^T
    BTp = x + (long)b * 4194304;
    out_off = (long)b * 4194304;
  }
  long Arow0 = (long)mt * 256;
  long Brow0 = (long)nt * 256;

  int rho = (w << 3) + (l >> 3);
  int csw = ((l & 7) ^ (l >> 3)) << 3;
  const u16* agA = Ap + (Arow0 + rho) * 1024 + csw;
  int browoff = (w >> 2) * 64 + (w & 3) * 8 + (l >> 3);
  const u16* agB = BTp + (Brow0 + browoff) * 1024 + csw;
  char* ldsAthr = lds + rho * 128 + (l & 7) * 16;
  char* ldsBthr = lds + 32768 + browoff * 128 + (l & 7) * 16;

  auto SA = [&](int dt, int st, int mh) {
    char* d = ldsAthr + (dt & 1) * 65536 + mh * 8192;
    const u16* s = agA + (long)st * 64 + mh * 65536;
    __builtin_amdgcn_global_load_lds(
        (const __attribute__((address_space(1))) void*)s,
        (__attribute__((address_space(3))) void*)d, 16, 0, 0);
    __builtin_amdgcn_global_load_lds(
        (const __attribute__((address_space(1))) void*)(s + 131072),
        (__attribute__((address_space(3))) void*)(d + 16384), 16, 0, 0);
  };
  auto SB = [&](int dt, int st, int h) {
    char* d = ldsBthr + (dt & 1) * 65536 + h * 4096;
    const u16* s = agB + (long)st * 64 + h * 32768;
    __builtin_amdgcn_global_load_lds(
        (const __attribute__((address_space(1))) void*)s,
        (__attribute__((address_space(3))) void*)d, 16, 0, 0);
    __builtin_amdgcn_global_load_lds(
        (const __attribute__((address_space(1))) void*)(s + 131072),
        (__attribute__((address_space(3))) void*)(d + 16384), 16, 0, 0);
  };

  int arow_b = (wr * 128 + lr) * 128;
  int brow_b = (wc * 64 + lr) * 128 + 32768;
  int xr0 = (lh ^ (lr & 7)) << 4;
  int xr1 = ((4 + lh) ^ (lr & 7)) << 4;

  f32x4 acc[8][4];
  #pragma unroll
  for (int m = 0; m < 8; ++m)
    #pragma unroll
    for (int n = 0; n < 4; ++n) acc[m][n] = f32x4{0.f, 0.f, 0.f, 0.f};

  bf16x8 af[4][2], bn0[2][2], bn1[2][2];

  auto RD_AF0 = [&](int buf) {
    #pragma unroll
    for (int m = 0; m < 4; ++m) {
      af[m][0] = *(const bf16x8*)(lds + buf + arow_b + m * 2048 + xr0);
      af[m][1] = *(const bf16x8*)(lds + buf + arow_b + m * 2048 + xr1);
    }
  };
  auto RD_AF1 = [&](int buf) {
    #pragma unroll
    for (int m = 0; m < 4; ++m) {
      af[m][0] = *(const bf16x8*)(lds + buf + arow_b + 8192 + m * 2048 + xr0);
      af[m][1] = *(const bf16x8*)(lds + buf + arow_b + 8192 + m * 2048 + xr1);
    }
  };
  auto RD_BN0 = [&](int buf) {
    #pragma unroll
    for (int n = 0; n < 2; ++n) {
      bn0[n][0] = *(const bf16x8*)(lds + buf + brow_b + n * 2048 + xr0);
      bn0[n][1] = *(const bf16x8*)(lds + buf + brow_b + n * 2048 + xr1);
    }
  };
  auto RD_BN1 = [&](int buf) {
    #pragma unroll
    for (int n = 0; n < 2; ++n) {
      bn1[n][0] = *(const bf16x8*)(lds + buf + brow_b + 4096 + n * 2048 + xr0);
      bn1[n][1] = *(const bf16x8*)(lds + buf + brow_b + 4096 + n * 2048 + xr1);
    }
  };
  auto Q = [&](int mo, int no, bf16x8 (&bn)[2][2]) {
    __builtin_amdgcn_s_setprio(1);
    #pragma unroll
    for (int m = 0; m < 4; ++m)
      #pragma unroll
      for (int n = 0; n < 2; ++n) {
        acc[mo + m][no + n] = MFMA16(af[m][0], bn[n][0], acc[mo + m][no + n]);
        acc[mo + m][no + n] = MFMA16(af[m][1], bn[n][1], acc[mo + m][no + n]);
      }
    __builtin_amdgcn_s_setprio(0);
  };

  SA(0, 0, 0); SA(0, 0, 1); SB(0, 0, 0); SB(0, 0, 1);
  SA(1, 1, 0); SA(1, 1, 1); SB(1, 1, 0);
  VM6(); GBAR();

  for (int i = 0; i < 8; ++i) {
    int t = 2 * i;
    RD_AF0(0); RD_BN0(0); SBAR0();
    SB(t + 1, t + 1, 1);
    GBAR(); LGKM0();
    Q(0, 0, bn0);
    GBAR();
    RD_BN1(0); SBAR0();
    { int tt = t + 2; SA(tt, tt < 16 ? tt : 15, 0); }
    GBAR(); LGKM0();
    Q(0, 2, bn1);
    GBAR();
    RD_AF1(0); SBAR0();
    { int tt = t + 2; SB(tt, tt < 16 ? tt : 15, 0); }
    GBAR(); LGKM0();
    Q(4, 0, bn0);
    GBAR();
    { int tt = t + 2; SA(tt, tt < 16 ? tt : 15, 1); }
    GBAR(); VM6();
    Q(4, 2, bn1);
    GBAR();
    RD_AF0(65536); RD_BN0(65536); SBAR0();
    { int tt = t + 2; SB(tt, tt < 16 ? tt : 15, 1); }
    GBAR(); LGKM0();
    Q(0, 0, bn0);
    GBAR();
    RD_BN1(65536); SBAR0();
    { int tt = t + 3; SA(tt, tt < 16 ? tt : 15, 0); }
    GBAR(); LGKM0();
    Q(0, 2, bn1);
    GBAR();
    RD_AF1(65536); SBAR0();
    { int tt = t + 3; SB(tt, tt < 16 ? tt : 15, 0); }
    GBAR(); LGKM0();
    Q(4, 0, bn0);
    GBAR();
    { int tt = t + 3; SA(tt, tt < 16 ? tt : 15, 1); }
    GBAR(); VM6();
    Q(4, 2, bn1);
    GBAR();
  }

  asm volatile("s_waitcnt vmcnt(0)" ::: "memory");

  #pragma unroll
  for (int m = 0; m < 8; ++m) {
    #pragma unroll
    for (int n = 0; n < 4; ++n) {
      #pragma unroll
      for (int r = 0; r < 4; ++r) {
        long row = Arow0 + wr * 128 + m * 16 + lh * 4 + r;
        long col = Brow0 + wc * 64 + n * 16 + lr;
        float v = acc[m][n][r];
        if (isK) {
          v += bias[col];
          long addr = (row >> 12) * 4194304 + (col >> 6) * 262144
                    + (row & 4095) * 64 + (col & 63);
          Kt[addr] = f2bf(v);
        } else {
          v += bias[1024 + row];
          Vt[out_off + row * 4096 + col] = f2bf(v);
        }
      }
    }
  }
}

// ---------------- 64x64x(K=1024) GEMM for the small matmuls ------------------
// 224 blocks (14 mt x 16 nt), 256 thr / 4 waves, XOR-swizzled LDS.
// MODE 2: A = y f32, reg-staged cvt (dest chunk sc, source chunk sc^(row&7)).
// MODE 3: A = a_bf bf16 via global_load_lds (dest sc, pre-swizzled source).
template<int MODE>
__global__ __launch_bounds__(256, 4) void gemm64(
    const void* __restrict__ Ap, const u16* __restrict__ BT,
    const float* __restrict__ bias, void* __restrict__ outp)
{
  __shared__ u16 As[64][64];
  __shared__ u16 Bs[64][64];

  int bid = blockIdx.x;
  int mt = bid >> 4, nt = bid & 15;
  int tid = threadIdx.x;
  int l = tid & 63, w = tid >> 6;
  int wr = w >> 1, wc = w & 1;
  int lr = l & 15, lh = l >> 4;

  f32x4 acc[2][2];
  #pragma unroll
  for (int m = 0; m < 2; ++m)
    #pragma unroll
    for (int n = 0; n < 2; ++n) acc[m][n] = f32x4{0.f, 0.f, 0.f, 0.f};

  long arow0 = (long)mt * 64;
  long brow0 = (long)nt * 64;
  int srow = tid >> 3, sc = tid & 7;

  for (int kt = 0; kt < 16; ++kt) {
    int ko = kt * 64;
    #pragma unroll
    for (int p = 0; p < 2; ++p) {
      int row = srow + p * 32;
      int cs = (sc ^ (row & 7)) << 3;
      __builtin_amdgcn_global_load_lds(
          (const __attribute__((address_space(1))) void*)(BT + (brow0 + row) * 1024 + ko + cs),
          (__attribute__((address_space(3))) void*)(&Bs[row][sc * 8]), 16, 0, 0);
      if constexpr (MODE == 3)
        __builtin_amdgcn_global_load_lds(
            (const __attribute__((address_space(1))) void*)((const u16*)Ap + (arow0 + row) * 1024 + ko + cs),
            (__attribute__((address_space(3))) void*)(&As[row][sc * 8]), 16, 0, 0);
    }
    if constexpr (MODE == 2) {
      #pragma unroll
      for (int p = 0; p < 2; ++p) {
        int row = srow + p * 32;
        int cs = (sc ^ (row & 7)) << 3;   // SOURCE chunk (pre-swizzled)
        ushort4 o0 = {0, 0, 0, 0}, o1 = {0, 0, 0, 0};
        if (arow0 + row < 784) {
          const float* src = (const float*)Ap + (arow0 + row) * 1024 + ko + cs;
          float4 f0 = *(const float4*)src;
          float4 f1 = *(const float4*)(src + 4);
          o0.x = f2bf(f0.x); o0.y = f2bf(f0.y); o0.z = f2bf(f0.z); o0.w = f2bf(f0.w);
          o1.x = f2bf(f1.x); o1.y = f2bf(f1.y); o1.z = f2bf(f1.z); o1.w = f2bf(f1.w);
        }
        *(ushort4*)(&As[row][sc * 8]) = o0;       // DEST chunk sc
        *(ushort4*)(&As[row][sc * 8 + 4]) = o1;
      }
    }
    __syncthreads();
    #pragma unroll
    for (int kk = 0; kk < 2; ++kk) {
      bf16x8 afr[2], bfr[2];
      #pragma unroll
      for (int m = 0; m < 2; ++m) {
        int row = wr * 32 + m * 16 + lr;
        afr[m] = *(const bf16x8*)((const char*)&As[row][0] + (((kk * 4 + lh) ^ (row & 7)) << 4));
      }
      #pragma unroll
      for (int n = 0; n < 2; ++n) {
        int row = wc * 32 + n * 16 + lr;
        bfr[n] = *(const bf16x8*)((const char*)&Bs[row][0] + (((kk * 4 + lh) ^ (row & 7)) << 4));
      }
      #pragma unroll
      for (int m = 0; m < 2; ++m)
        #pragma unroll
        for (int n = 0; n < 2; ++n)
          acc[m][n] = MFMA16(afr[m], bfr[n], acc[m][n]);
    }
    __syncthreads();
  }

  #pragma unroll
  for (int m = 0; m < 2; ++m) {
    #pragma unroll
    for (int n = 0; n < 2; ++n) {
      #pragma unroll
      for (int r = 0; r < 4; ++r) {
        int row = (int)arow0 + wr * 32 + m * 16 + lh * 4 + r;
        int col = (int)brow0 + wc * 32 + n * 16 + lr;
        if (row < 784) {
          float v = acc[m][n][r] + bias[col];
          if constexpr (MODE == 2) {
            int b = row / 49, qi = row - b * 49;
            long addr = ((long)(b * 16 + (col >> 6)) * 64 + qi) * 64 + (col & 63);
            ((u16*)outp)[addr] = f2bf(v);
          } else {
            ((float*)outp)[(long)row * 1024 + col] = v;
          }
        }
      }
    }
  }
}

// ---------------- fused attention partials: LDS-staged streaming -------------
// One wg per (bh, s-chunk of 1024). 4 chunks -> grid 1024 = exactly 4 wg/CU.
__global__ __launch_bounds__(256, 4) void attn_part(
    const u16* __restrict__ Kt, const u16* __restrict__ Vt, const u16* __restrict__ Q,
    const u16* __restrict__ maskT,
    float* __restrict__ partA, float* __restrict__ prs)
{
  __shared__ __align__(16) char lds[40960];

  int bh = blockIdx.x, chunk = blockIdx.y;
  int tid = threadIdx.x;
  int l = tid & 63, w = tid >> 6;
  int lr = l & 15, lh = l >> 4;

  const u16* Kb = Kt + (long)bh * 262144;
  const u16* Vb = Vt + (long)bh * 262144;
  const u16* Qb = Q + (long)bh * 4096;

  int t0 = chunk * 16;
  const int nt = 16;
  int tmax = t0 + nt - 1;

  int strow = tid >> 3;
  int sc = tid & 7;

  auto STAGE = [&](int buf, int tt) {
    long s0 = (long)tt * 64;
    #pragma unroll
    for (int h = 0; h < 2; ++h) {
      int row = h * 32 + strow;
      int cs = (sc ^ (row & 7)) << 3;
      const u16* ksrc = Kb + (s0 + row) * 64 + cs;
      char* kdst = lds + buf * 8192 + row * 128 + sc * 16;
      __builtin_amdgcn_global_load_lds(
          (const __attribute__((address_space(1))) void*)ksrc,
          (__attribute__((address_space(3))) void*)kdst, 16, 0, 0);
      const u16* vsrc = Vb + (long)row * 4096 + s0 + cs;
      char* vdst = lds + 16384 + buf * 8192 + row * 128 + sc * 16;
      __builtin_amdgcn_global_load_lds(
          (const __attribute__((address_space(1))) void*)vsrc,
          (__attribute__((address_space(3))) void*)vdst, 16, 0, 0);
    }
  };

  bf16x8 qf[2];
  #pragma unroll
  for (int kf2 = 0; kf2 < 2; ++kf2)
    qf[kf2] = *(const bf16x8*)(Qb + (w * 16 + lr) * 64 + kf2 * 32 + lh * 8);

  bf16x8 ones;
  #pragma unroll
  for (int j = 0; j < 8; ++j) ones[j] = (__bf16)1.0f;

  f32x4 acc_a[4];
  #pragma unroll
  for (int n = 0; n < 4; ++n) acc_a[n] = f32x4{0.f, 0.f, 0.f, 0.f};
  f32x4 acc_rs = f32x4{0.f, 0.f, 0.f, 0.f};

  char* Pw = lds + 32768 + w * 2048;
  const u16* mbase = maskT + w * 16 + lh * 4;

  STAGE(0, t0);
  STAGE(1, t0 + 1);
  ushort4 mvu[4];
  #pragma unroll
  for (int sf = 0; sf < 4; ++sf)
    mvu[sf] = *(const ushort4*)(mbase + ((long)t0 * 64 + sf * 16 + lr) * 64);
  VM8();
  GBAR();

  for (int it = 0; it < nt; ++it) {
    int buf = it & 1;
    const char* Kl = lds + buf * 8192;
    const char* Vl = lds + 16384 + buf * 8192;

    int tn = it + 1 < nt ? t0 + it + 1 : tmax;
    ushort4 mvn[4];
    #pragma unroll
    for (int sf = 0; sf < 4; ++sf)
      mvn[sf] = *(const ushort4*)(mbase + ((long)tn * 64 + sf * 16 + lr) * 64);

    bf16x8 kf[4][2];
    #pragma unroll
    for (int sf = 0; sf < 4; ++sf) {
      int srw = sf * 16 + lr;
      int xb = srw & 7;
      kf[sf][0] = *(const bf16x8*)(Kl + srw * 128 + ((lh ^ xb) << 4));
      kf[sf][1] = *(const bf16x8*)(Kl + srw * 128 + (((4 + lh) ^ xb) << 4));
    }
    f32x4 lg[4];
    #pragma unroll
    for (int sf = 0; sf < 4; ++sf) {
      f32x4 t = f32x4{0.f, 0.f, 0.f, 0.f};
      t = MFMA16(qf[0], kf[sf][0], t);
      t = MFMA16(qf[1], kf[sf][1], t);
      lg[sf] = t;
    }

    bf16x8 vf[2][4];
    #pragma unroll
    for (int k2 = 0; k2 < 2; ++k2)
      #pragma unroll
      for (int n = 0; n < 4; ++n) {
        int vrow = n * 16 + lr;
        vf[k2][n] = *(const bf16x8*)(Vl + vrow * 128 + (((k2 * 4 + lh) ^ (lr & 7)) << 4));
      }

    #pragma unroll
    for (int sf = 0; sf < 4; ++sf) {
      #pragma unroll
      for (int r = 0; r < 4; ++r) {
        int qq = lh * 4 + r;
        float e = __expf(lg[sf][r] * 0.125f) * bfu(mvu[sf], r);
        int byte = (qq * 128 + (sf * 16 + lr) * 2) ^ ((qq & 7) << 4);
        *(u16*)(Pw + byte) = f2bf(e);
      }
    }

    #pragma unroll
    for (int k2 = 0; k2 < 2; ++k2) {
      int byte = (lr * 128 + k2 * 64 + lh * 16) ^ ((lr & 7) << 4);
      bf16x8 pf;
      __builtin_memcpy(&pf, Pw + byte, 16);
      #pragma unroll
      for (int n = 0; n < 4; ++n)
        acc_a[n] = MFMA16(pf, vf[k2][n], acc_a[n]);
      acc_rs = MFMA16(pf, ones, acc_rs);
    }

    LGKM0();
    GBAR();
    { int tt = it + 2 < nt ? t0 + it + 2 : tmax; STAGE(buf, tt); }
    VM8();
    GBAR();

    #pragma unroll
    for (int sf = 0; sf < 4; ++sf) mvu[sf] = mvn[sf];
  }

  long base = ((long)bh * 4 + chunk) * 64;
  #pragma unroll
  for (int r = 0; r < 4; ++r) {
    int q = w * 16 + lh * 4 + r;
    if (lr == 0) prs[base + q] = acc_rs[r];
    #pragma unroll
    for (int n = 0; n < 4; ++n)
      partA[(base + q) * 64 + n * 16 + lr] = acc_a[n][r];
  }
}

// ---------------- reduce 4 s-chunk partials, normalize, write a_bf -----------
__global__ __launch_bounds__(256) void attn_reduce(
    const float* __restrict__ partA, const float* __restrict__ prs,
    u16* __restrict__ Abf)
{
  int bh = blockIdx.x;
  int t = threadIdx.x;
  int q = t >> 2, d0 = (t & 3) * 16;
  if (q >= 49) return;
  int b = bh >> 4, h = bh & 15;

  float rs = 1e-6f;
  #pragma unroll
  for (int c = 0; c < 4; ++c) rs += prs[((long)bh * 4 + c) * 64 + q];

  #pragma unroll
  for (int j = 0; j < 4; ++j) {
    float4 s = float4{0.f, 0.f, 0.f, 0.f};
    #pragma unroll
    for (int c = 0; c < 4; ++c) {
      float4 v = *(const float4*)(partA + (((long)bh * 4 + c) * 64 + q) * 64 + d0 + j * 4);
      s.x += v.x; s.y += v.y; s.z += v.z; s.w += v.w;
    }
    ushort4 o;
    o.x = f2bf(s.x / rs); o.y = f2bf(s.y / rs);
    o.z = f2bf(s.z / rs); o.w = f2bf(s.w / rs);
    *(ushort4*)(Abf + ((long)(b * 49 + q) * 1024 + h * 64 + d0 + j * 4)) = o;
  }
}

// -----------------------------------------------------------------------------
extern "C" void kernel_launch(void* const* d_in, const int* in_sizes, int n_in,
                              void* d_out, int out_size, void* d_ws, size_t ws_size,
                              hipStream_t stream) {
  const float* x      = (const float*)d_in[0];
  const float* y      = (const float*)d_in[1];
  const float* mask   = (const float*)d_in[2];
  const float* W_attn = (const float*)d_in[3];
  const float* b_attn = (const float*)d_in[4];
  const float* W_mlp  = (const float*)d_in[5];
  const float* b_mlp  = (const float*)d_in[6];
  const float* W_proj = (const float*)d_in[7];
  const float* b_proj = (const float*)d_in[8];

  if (ws_size < 417333248ULL) return;

  char* ws = (char*)d_ws;
  u16* x_bf    = (u16*)(ws);                   // 128 MB  [65536][1024]
  u16* Kt      = (u16*)(ws + 134217728L);      // 128 MB  [b][h][s][d]
  u16* Vt      = (u16*)(ws + 268435456L);      // 128 MB  [b][h][d][s]
  u16* WT_attn = (u16*)(ws + 402653184L);      // 4 MB    [2048][1024]
  u16* WT_mlp  = (u16*)(ws + 406847488L);      // 2 MB
  u16* WT_proj = (u16*)(ws + 408944640L);      // 2 MB
  u16* q_ws    = (u16*)(ws + 412876800L);      // 2 MB    [b][h][64][64]
  u16* a_bf    = (u16*)(ws + 414973952L);      // 1.75 MB [896][1024]
  u16* maskT   = (u16*)(ws + 416808960L);      // 512 KB  [4096][64] bf16
  // attention partials REUSE the x_bf region (dead after gemm256kv)
  float* partA = (float*)(ws);                 // 16 MB   [bh][chunk4][64q][64d]
  float* prs   = (float*)(ws + 16777216L);     // 256 KB  [bh][chunk4][64q]

  cast_f32_bf16<<<2048, 256, 0, stream>>>(x, x_bf, 16777216);
  transpose_all<<<dim3(32, 16, 3), 256, 0, stream>>>(W_attn, W_mlp, W_proj,
                                                     WT_attn, WT_mlp, WT_proj);
  mask_prep<<<64, 256, 0, stream>>>(mask, maskT);

  gemm256kv<<<dim3(1024, 2), 512, 0, stream>>>(x_bf, WT_attn, b_attn, Kt, Vt);
  gemm64<2><<<224, 256, 0, stream>>>(y, WT_mlp, b_mlp, q_ws);

  attn_part<<<dim3(256, 4), 256, 0, stream>>>(Kt, Vt, q_ws, maskT, partA, prs);
  attn_reduce<<<256, 256, 0, stream>>>(partA, prs, a_bf);

  gemm64<3><<<224, 256, 0, stream>>>(a_bf, WT_proj, b_proj, d_out);
}

// Round 13
// 462.837 us; speedup vs baseline: 1.6061x; 1.2002x over previous
//
#include <hip/hip_runtime.h>
#include <cstdint>

typedef __bf16 bf16x8 __attribute__((ext_vector_type(8)));
typedef float f32x4 __attribute__((ext_vector_type(4)));
typedef unsigned short u16;

#define GBAR() asm volatile("s_barrier" ::: "memory")
#define SBAR0() __builtin_amdgcn_sched_barrier(0)
#define LGKM0() do { asm volatile("s_waitcnt lgkmcnt(0)" ::: "memory"); SBAR0(); } while (0)
#define VM6()  asm volatile("s_waitcnt vmcnt(6)" ::: "memory")
#define VM8()  asm volatile("s_waitcnt vmcnt(8)" ::: "memory")
#define MFMA16(a, b, c) __builtin_amdgcn_mfma_f32_16x16x32_bf16((a), (b), (c), 0, 0, 0)

__device__ __forceinline__ u16 f2bf(float f) {
  unsigned u = __builtin_bit_cast(unsigned, f);
  u += 0x7fffu + ((u >> 16) & 1u);   // RNE, matches numpy/jax bf16 cast
  return (u16)(u >> 16);
}
__device__ __forceinline__ float bfu(ushort4 v, int r) {
  unsigned short s = (r == 0) ? v.x : (r == 1) ? v.y : (r == 2) ? v.z : v.w;
  return __builtin_bit_cast(float, (unsigned)s << 16);
}

// ---------------- cast f32 -> bf16 (x only) ----------------------------------
__global__ void cast_f32_bf16(const float* __restrict__ in, u16* __restrict__ out,
                              int n4) {
  int i = blockIdx.x * blockDim.x + threadIdx.x;
  int stride = gridDim.x * blockDim.x;
  for (; i < n4; i += stride) {
    float4 v = ((const float4*)in)[i];
    ushort4 o;
    o.x = f2bf(v.x); o.y = f2bf(v.y); o.z = f2bf(v.z); o.w = f2bf(v.w);
    ((ushort4*)out)[i] = o;
  }
}

// ------- batched transpose+cast: 3 weight matrices + mask (z==3) -------------
__global__ void transpose_all(const float* __restrict__ Wa, const float* __restrict__ Wm,
                              const float* __restrict__ Wp, const float* __restrict__ mask,
                              u16* __restrict__ oa, u16* __restrict__ om,
                              u16* __restrict__ op, u16* __restrict__ omask) {
  __shared__ float t[64][65];
  int z = blockIdx.z;
  int c = threadIdx.x & 63, r0 = threadIdx.x >> 6;
  if (z == 3) {
    // mask: in [49][4096] f32 -> out [4096][64] bf16 (q zero-padded to 64)
    int bidf = blockIdx.y * 32 + blockIdx.x;
    if (bidf >= 64) return;
    int s0 = bidf * 64;
    #pragma unroll
    for (int p = 0; p < 16; ++p) {
      int q = p * 4 + r0;
      t[q][c] = (q < 49) ? mask[(long)q * 4096 + s0 + c] : 0.f;
    }
    __syncthreads();
    #pragma unroll
    for (int p = 0; p < 16; ++p) {
      int r = p * 4 + r0;
      omask[(long)(s0 + r) * 64 + c] = f2bf(t[c][r]);
    }
    return;
  }
  const float* in = (z == 0) ? Wa : (z == 1) ? Wm : Wp;
  u16* out = (z == 0) ? oa : (z == 1) ? om : op;
  int C = (z == 0) ? 2048 : 1024;
  const int R = 1024;
  if (blockIdx.x * 64 >= C) return;
  int tc = blockIdx.x * 64, tr = blockIdx.y * 64;
  #pragma unroll
  for (int p = 0; p < 16; ++p) {
    int r = p * 4 + r0;
    t[r][c] = in[(long)(tr + r) * C + (tc + c)];
  }
  __syncthreads();
  #pragma unroll
  for (int p = 0; p < 16; ++p) {
    int r = p * 4 + r0;
    out[(long)(tc + r) * R + (tr + c)] = f2bf(t[c][r]);
  }
}

// =============== 256x256x(K=1024) bf16 GEMM, m201 8-phase template ===========
// Round-10 configuration (proven 465us) — GEMM core frozen.
template<int MODE>
__global__ __launch_bounds__(512, 2) void gemm256(
    const u16* __restrict__ A, const u16* __restrict__ BT,
    const float* __restrict__ bias, void* __restrict__ outp)
{
  __shared__ __align__(16) char lds[131072];  // [2 buf][A 32K | B 32K]

  int tid = threadIdx.x;
  int l = tid & 63, w = tid >> 6;
  int wr = w >> 2, wc = w & 3;
  int lr = l & 15, lh = l >> 4;

  int bid = blockIdx.x;
  int mt, nt;
  long out_off = 0;
  const u16* Ap = A;
  const u16* BTp = BT;
  if constexpr (MODE == 0) {
    int wg = (bid & 7) * 128 + (bid >> 3);   // XCD-contiguous (1024 % 8 == 0)
    mt = wg >> 2; nt = wg & 3;
  } else {
    int wg = (bid & 7) * 8 + (bid >> 3);     // 64 blocks per batch
    mt = wg & 3; nt = wg >> 2;
    int b = blockIdx.y;
    BTp = BT + (long)b * 4194304;
    out_off = (long)b * 4194304;
  }
  long Arow0 = (long)mt * 256;
  long Brow0 = (long)nt * 256;

  int rho = (w << 3) + (l >> 3);
  int csw = ((l & 7) ^ (l >> 3)) << 3;
  const u16* agA = Ap + (Arow0 + rho) * 1024 + csw;
  int browoff = (w >> 2) * 64 + (w & 3) * 8 + (l >> 3);
  const u16* agB = BTp + (Brow0 + browoff) * 1024 + csw;
  char* ldsAthr = lds + rho * 128 + (l & 7) * 16;
  char* ldsBthr = lds + 32768 + browoff * 128 + (l & 7) * 16;

  auto SA = [&](int dt, int st, int mh) {
    char* d = ldsAthr + (dt & 1) * 65536 + mh * 8192;
    const u16* s = agA + (long)st * 64 + mh * 65536;
    __builtin_amdgcn_global_load_lds(
        (const __attribute__((address_space(1))) void*)s,
        (__attribute__((address_space(3))) void*)d, 16, 0, 0);
    __builtin_amdgcn_global_load_lds(
        (const __attribute__((address_space(1))) void*)(s + 131072),
        (__attribute__((address_space(3))) void*)(d + 16384), 16, 0, 0);
  };
  auto SB = [&](int dt, int st, int h) {
    char* d = ldsBthr + (dt & 1) * 65536 + h * 4096;
    const u16* s = agB + (long)st * 64 + h * 32768;
    __builtin_amdgcn_global_load_lds(
        (const __attribute__((address_space(1))) void*)s,
        (__attribute__((address_space(3))) void*)d, 16, 0, 0);
    __builtin_amdgcn_global_load_lds(
        (const __attribute__((address_space(1))) void*)(s + 131072),
        (__attribute__((address_space(3))) void*)(d + 16384), 16, 0, 0);
  };

  int arow_b = (wr * 128 + lr) * 128;
  int brow_b = (wc * 64 + lr) * 128 + 32768;
  int xr0 = (lh ^ (lr & 7)) << 4;
  int xr1 = ((4 + lh) ^ (lr & 7)) << 4;

  f32x4 acc[8][4];
  #pragma unroll
  for (int m = 0; m < 8; ++m)
    #pragma unroll
    for (int n = 0; n < 4; ++n) acc[m][n] = f32x4{0.f, 0.f, 0.f, 0.f};

  bf16x8 af[4][2], bn0[2][2], bn1[2][2];

  auto RD_AF0 = [&](int buf) {
    #pragma unroll
    for (int m = 0; m < 4; ++m) {
      af[m][0] = *(const bf16x8*)(lds + buf + arow_b + m * 2048 + xr0);
      af[m][1] = *(const bf16x8*)(lds + buf + arow_b + m * 2048 + xr1);
    }
  };
  auto RD_AF1 = [&](int buf) {
    #pragma unroll
    for (int m = 0; m < 4; ++m) {
      af[m][0] = *(const bf16x8*)(lds + buf + arow_b + 8192 + m * 2048 + xr0);
      af[m][1] = *(const bf16x8*)(lds + buf + arow_b + 8192 + m * 2048 + xr1);
    }
  };
  auto RD_BN0 = [&](int buf) {
    #pragma unroll
    for (int n = 0; n < 2; ++n) {
      bn0[n][0] = *(const bf16x8*)(lds + buf + brow_b + n * 2048 + xr0);
      bn0[n][1] = *(const bf16x8*)(lds + buf + brow_b + n * 2048 + xr1);
    }
  };
  auto RD_BN1 = [&](int buf) {
    #pragma unroll
    for (int n = 0; n < 2; ++n) {
      bn1[n][0] = *(const bf16x8*)(lds + buf + brow_b + 4096 + n * 2048 + xr0);
      bn1[n][1] = *(const bf16x8*)(lds + buf + brow_b + 4096 + n * 2048 + xr1);
    }
  };
  auto Q = [&](int mo, int no, bf16x8 (&bn)[2][2]) {
    __builtin_amdgcn_s_setprio(1);
    #pragma unroll
    for (int m = 0; m < 4; ++m)
      #pragma unroll
      for (int n = 0; n < 2; ++n) {
        acc[mo + m][no + n] = MFMA16(af[m][0], bn[n][0], acc[mo + m][no + n]);
        acc[mo + m][no + n] = MFMA16(af[m][1], bn[n][1], acc[mo + m][no + n]);
      }
    __builtin_amdgcn_s_setprio(0);
  };

  SA(0, 0, 0); SA(0, 0, 1); SB(0, 0, 0); SB(0, 0, 1);
  SA(1, 1, 0); SA(1, 1, 1); SB(1, 1, 0);
  VM6(); GBAR();

  for (int i = 0; i < 8; ++i) {
    int t = 2 * i;
    RD_AF0(0); RD_BN0(0); SBAR0();
    SB(t + 1, t + 1, 1);
    GBAR(); LGKM0();
    Q(0, 0, bn0);
    GBAR();
    RD_BN1(0); SBAR0();
    { int tt = t + 2; SA(tt, tt < 16 ? tt : 15, 0); }
    GBAR(); LGKM0();
    Q(0, 2, bn1);
    GBAR();
    RD_AF1(0); SBAR0();
    { int tt = t + 2; SB(tt, tt < 16 ? tt : 15, 0); }
    GBAR(); LGKM0();
    Q(4, 0, bn0);
    GBAR();
    { int tt = t + 2; SA(tt, tt < 16 ? tt : 15, 1); }
    GBAR(); VM6();
    Q(4, 2, bn1);
    GBAR();
    RD_AF0(65536); RD_BN0(65536); SBAR0();
    { int tt = t + 2; SB(tt, tt < 16 ? tt : 15, 1); }
    GBAR(); LGKM0();
    Q(0, 0, bn0);
    GBAR();
    RD_BN1(65536); SBAR0();
    { int tt = t + 3; SA(tt, tt < 16 ? tt : 15, 0); }
    GBAR(); LGKM0();
    Q(0, 2, bn1);
    GBAR();
    RD_AF1(65536); SBAR0();
    { int tt = t + 3; SB(tt, tt < 16 ? tt : 15, 0); }
    GBAR(); LGKM0();
    Q(4, 0, bn0);
    GBAR();
    { int tt = t + 3; SA(tt, tt < 16 ? tt : 15, 1); }
    GBAR(); VM6();
    Q(4, 2, bn1);
    GBAR();
  }

  asm volatile("s_waitcnt vmcnt(0)" ::: "memory");

  #pragma unroll
  for (int m = 0; m < 8; ++m) {
    #pragma unroll
    for (int n = 0; n < 4; ++n) {
      #pragma unroll
      for (int r = 0; r < 4; ++r) {
        long row = Arow0 + wr * 128 + m * 16 + lh * 4 + r;
        long col = Brow0 + wc * 64 + n * 16 + lr;
        float v = acc[m][n][r];
        if constexpr (MODE == 0) {
          v += bias[col];
          long addr = (row >> 12) * 4194304 + (col >> 6) * 262144
                    + (row & 4095) * 64 + (col & 63);
          ((u16*)outp)[addr] = f2bf(v);
        } else {
          v += bias[1024 + row];
          ((u16*)outp)[out_off + row * 4096 + col] = f2bf(v);
        }
      }
    }
  }
}

// ---------------- 64x64x(K=1024) GEMM for the small matmuls ------------------
template<int MODE>
__global__ __launch_bounds__(256, 4) void gemm64(
    const void* __restrict__ Ap, const u16* __restrict__ BT,
    const float* __restrict__ bias, void* __restrict__ outp)
{
  __shared__ u16 As[64][64];
  __shared__ u16 Bs[64][64];

  int bid = blockIdx.x;
  int mt = bid >> 4, nt = bid & 15;
  int tid = threadIdx.x;
  int l = tid & 63, w = tid >> 6;
  int wr = w >> 1, wc = w & 1;
  int lr = l & 15, lh = l >> 4;

  f32x4 acc[2][2];
  #pragma unroll
  for (int m = 0; m < 2; ++m)
    #pragma unroll
    for (int n = 0; n < 2; ++n) acc[m][n] = f32x4{0.f, 0.f, 0.f, 0.f};

  long arow0 = (long)mt * 64;
  long brow0 = (long)nt * 64;
  int srow = tid >> 3, sc = tid & 7;

  for (int kt = 0; kt < 16; ++kt) {
    int ko = kt * 64;
    #pragma unroll
    for (int p = 0; p < 2; ++p) {
      int row = srow + p * 32;
      int cs = (sc ^ (row & 7)) << 3;
      __builtin_amdgcn_global_load_lds(
          (const __attribute__((address_space(1))) void*)(BT + (brow0 + row) * 1024 + ko + cs),
          (__attribute__((address_space(3))) void*)(&Bs[row][sc * 8]), 16, 0, 0);
      if constexpr (MODE == 3)
        __builtin_amdgcn_global_load_lds(
            (const __attribute__((address_space(1))) void*)((const u16*)Ap + (arow0 + row) * 1024 + ko + cs),
            (__attribute__((address_space(3))) void*)(&As[row][sc * 8]), 16, 0, 0);
    }
    if constexpr (MODE == 2) {
      #pragma unroll
      for (int p = 0; p < 2; ++p) {
        int row = srow + p * 32;
        int cs = (sc ^ (row & 7)) << 3;   // SOURCE chunk (pre-swizzled)
        ushort4 o0 = {0, 0, 0, 0}, o1 = {0, 0, 0, 0};
        if (arow0 + row < 784) {
          const float* src = (const float*)Ap + (arow0 + row) * 1024 + ko + cs;
          float4 f0 = *(const float4*)src;
          float4 f1 = *(const float4*)(src + 4);
          o0.x = f2bf(f0.x); o0.y = f2bf(f0.y); o0.z = f2bf(f0.z); o0.w = f2bf(f0.w);
          o1.x = f2bf(f1.x); o1.y = f2bf(f1.y); o1.z = f2bf(f1.z); o1.w = f2bf(f1.w);
        }
        *(ushort4*)(&As[row][sc * 8]) = o0;       // DEST chunk sc
        *(ushort4*)(&As[row][sc * 8 + 4]) = o1;
      }
    }
    __syncthreads();
    #pragma unroll
    for (int kk = 0; kk < 2; ++kk) {
      bf16x8 afr[2], bfr[2];
      #pragma unroll
      for (int m = 0; m < 2; ++m) {
        int row = wr * 32 + m * 16 + lr;
        afr[m] = *(const bf16x8*)((const char*)&As[row][0] + (((kk * 4 + lh) ^ (row & 7)) << 4));
      }
      #pragma unroll
      for (int n = 0; n < 2; ++n) {
        int row = wc * 32 + n * 16 + lr;
        bfr[n] = *(const bf16x8*)((const char*)&Bs[row][0] + (((kk * 4 + lh) ^ (row & 7)) << 4));
      }
      #pragma unroll
      for (int m = 0; m < 2; ++m)
        #pragma unroll
        for (int n = 0; n < 2; ++n)
          acc[m][n] = MFMA16(afr[m], bfr[n], acc[m][n]);
    }
    __syncthreads();
  }

  #pragma unroll
  for (int m = 0; m < 2; ++m) {
    #pragma unroll
    for (int n = 0; n < 2; ++n) {
      #pragma unroll
      for (int r = 0; r < 4; ++r) {
        int row = (int)arow0 + wr * 32 + m * 16 + lh * 4 + r;
        int col = (int)brow0 + wc * 32 + n * 16 + lr;
        if (row < 784) {
          float v = acc[m][n][r] + bias[col];
          if constexpr (MODE == 2) {
            int b = row / 49, qi = row - b * 49;
            long addr = ((long)(b * 16 + (col >> 6)) * 64 + qi) * 64 + (col & 63);
            ((u16*)outp)[addr] = f2bf(v);
          } else {
            ((float*)outp)[(long)row * 1024 + col] = v;
          }
        }
      }
    }
  }
}

// ---------------- fused attention partials: LDS-staged streaming -------------
__global__ __launch_bounds__(256, 4) void attn_part(
    const u16* __restrict__ Kt, const u16* __restrict__ Vt, const u16* __restrict__ Q,
    const u16* __restrict__ maskT,
    float* __restrict__ partA, float* __restrict__ prs)
{
  __shared__ __align__(16) char lds[40960];

  int bh = blockIdx.x, chunk = blockIdx.y;
  int tid = threadIdx.x;
  int l = tid & 63, w = tid >> 6;
  int lr = l & 15, lh = l >> 4;

  const u16* Kb = Kt + (long)bh * 262144;
  const u16* Vb = Vt + (long)bh * 262144;
  const u16* Qb = Q + (long)bh * 4096;

  int t0 = chunk * 16;
  const int nt = 16;
  int tmax = t0 + nt - 1;

  int strow = tid >> 3;
  int sc = tid & 7;

  auto STAGE = [&](int buf, int tt) {
    long s0 = (long)tt * 64;
    #pragma unroll
    for (int h = 0; h < 2; ++h) {
      int row = h * 32 + strow;
      int cs = (sc ^ (row & 7)) << 3;
      const u16* ksrc = Kb + (s0 + row) * 64 + cs;
      char* kdst = lds + buf * 8192 + row * 128 + sc * 16;
      __builtin_amdgcn_global_load_lds(
          (const __attribute__((address_space(1))) void*)ksrc,
          (__attribute__((address_space(3))) void*)kdst, 16, 0, 0);
      const u16* vsrc = Vb + (long)row * 4096 + s0 + cs;
      char* vdst = lds + 16384 + buf * 8192 + row * 128 + sc * 16;
      __builtin_amdgcn_global_load_lds(
          (const __attribute__((address_space(1))) void*)vsrc,
          (__attribute__((address_space(3))) void*)vdst, 16, 0, 0);
    }
  };

  bf16x8 qf[2];
  #pragma unroll
  for (int kf2 = 0; kf2 < 2; ++kf2)
    qf[kf2] = *(const bf16x8*)(Qb + (w * 16 + lr) * 64 + kf2 * 32 + lh * 8);

  bf16x8 ones;
  #pragma unroll
  for (int j = 0; j < 8; ++j) ones[j] = (__bf16)1.0f;

  f32x4 acc_a[4];
  #pragma unroll
  for (int n = 0; n < 4; ++n) acc_a[n] = f32x4{0.f, 0.f, 0.f, 0.f};
  f32x4 acc_rs = f32x4{0.f, 0.f, 0.f, 0.f};

  char* Pw = lds + 32768 + w * 2048;
  const u16* mbase = maskT + w * 16 + lh * 4;

  STAGE(0, t0);
  STAGE(1, t0 + 1);
  ushort4 mvu[4];
  #pragma unroll
  for (int sf = 0; sf < 4; ++sf)
    mvu[sf] = *(const ushort4*)(mbase + ((long)t0 * 64 + sf * 16 + lr) * 64);
  VM8();
  GBAR();

  for (int it = 0; it < nt; ++it) {
    int buf = it & 1;
    const char* Kl = lds + buf * 8192;
    const char* Vl = lds + 16384 + buf * 8192;

    int tn = it + 1 < nt ? t0 + it + 1 : tmax;
    ushort4 mvn[4];
    #pragma unroll
    for (int sf = 0; sf < 4; ++sf)
      mvn[sf] = *(const ushort4*)(mbase + ((long)tn * 64 + sf * 16 + lr) * 64);

    bf16x8 kf[4][2];
    #pragma unroll
    for (int sf = 0; sf < 4; ++sf) {
      int srw = sf * 16 + lr;
      int xb = srw & 7;
      kf[sf][0] = *(const bf16x8*)(Kl + srw * 128 + ((lh ^ xb) << 4));
      kf[sf][1] = *(const bf16x8*)(Kl + srw * 128 + (((4 + lh) ^ xb) << 4));
    }
    f32x4 lg[4];
    #pragma unroll
    for (int sf = 0; sf < 4; ++sf) {
      f32x4 t = f32x4{0.f, 0.f, 0.f, 0.f};
      t = MFMA16(qf[0], kf[sf][0], t);
      t = MFMA16(qf[1], kf[sf][1], t);
      lg[sf] = t;
    }

    bf16x8 vf[2][4];
    #pragma unroll
    for (int k2 = 0; k2 < 2; ++k2)
      #pragma unroll
      for (int n = 0; n < 4; ++n) {
        int vrow = n * 16 + lr;
        vf[k2][n] = *(const bf16x8*)(Vl + vrow * 128 + (((k2 * 4 + lh) ^ (lr & 7)) << 4));
      }

    #pragma unroll
    for (int sf = 0; sf < 4; ++sf) {
      #pragma unroll
      for (int r = 0; r < 4; ++r) {
        int qq = lh * 4 + r;
        float e = __expf(lg[sf][r] * 0.125f) * bfu(mvu[sf], r);
        int byte = (qq * 128 + (sf * 16 + lr) * 2) ^ ((qq & 7) << 4);
        *(u16*)(Pw + byte) = f2bf(e);
      }
    }

    #pragma unroll
    for (int k2 = 0; k2 < 2; ++k2) {
      int byte = (lr * 128 + k2 * 64 + lh * 16) ^ ((lr & 7) << 4);
      bf16x8 pf;
      __builtin_memcpy(&pf, Pw + byte, 16);
      #pragma unroll
      for (int n = 0; n < 4; ++n)
        acc_a[n] = MFMA16(pf, vf[k2][n], acc_a[n]);
      acc_rs = MFMA16(pf, ones, acc_rs);
    }

    LGKM0();
    GBAR();
    { int tt = it + 2 < nt ? t0 + it + 2 : tmax; STAGE(buf, tt); }
    VM8();
    GBAR();

    #pragma unroll
    for (int sf = 0; sf < 4; ++sf) mvu[sf] = mvn[sf];
  }

  long base = ((long)bh * 4 + chunk) * 64;
  #pragma unroll
  for (int r = 0; r < 4; ++r) {
    int q = w * 16 + lh * 4 + r;
    if (lr == 0) prs[base + q] = acc_rs[r];
    #pragma unroll
    for (int n = 0; n < 4; ++n)
      partA[(base + q) * 64 + n * 16 + lr] = acc_a[n][r];
  }
}

// ---------------- reduce 4 s-chunk partials, normalize, write a_bf -----------
__global__ __launch_bounds__(256) void attn_reduce(
    const float* __restrict__ partA, const float* __restrict__ prs,
    u16* __restrict__ Abf)
{
  int bh = blockIdx.x;
  int t = threadIdx.x;
  int q = t >> 2, d0 = (t & 3) * 16;
  if (q >= 49) return;
  int b = bh >> 4, h = bh & 15;

  float rs = 1e-6f;
  #pragma unroll
  for (int c = 0; c < 4; ++c) rs += prs[((long)bh * 4 + c) * 64 + q];

  #pragma unroll
  for (int j = 0; j < 4; ++j) {
    float4 s = float4{0.f, 0.f, 0.f, 0.f};
    #pragma unroll
    for (int c = 0; c < 4; ++c) {
      float4 v = *(const float4*)(partA + (((long)bh * 4 + c) * 64 + q) * 64 + d0 + j * 4);
      s.x += v.x; s.y += v.y; s.z += v.z; s.w += v.w;
    }
    ushort4 o;
    o.x = f2bf(s.x / rs); o.y = f2bf(s.y / rs);
    o.z = f2bf(s.z / rs); o.w = f2bf(s.w / rs);
    *(ushort4*)(Abf + ((long)(b * 49 + q) * 1024 + h * 64 + d0 + j * 4)) = o;
  }
}

// -----------------------------------------------------------------------------
extern "C" void kernel_launch(void* const* d_in, const int* in_sizes, int n_in,
                              void* d_out, int out_size, void* d_ws, size_t ws_size,
                              hipStream_t stream) {
  const float* x      = (const float*)d_in[0];
  const float* y      = (const float*)d_in[1];
  const float* mask   = (const float*)d_in[2];
  const float* W_attn = (const float*)d_in[3];
  const float* b_attn = (const float*)d_in[4];
  const float* W_mlp  = (const float*)d_in[5];
  const float* b_mlp  = (const float*)d_in[6];
  const float* W_proj = (const float*)d_in[7];
  const float* b_proj = (const float*)d_in[8];

  if (ws_size < 417333248ULL) return;

  char* ws = (char*)d_ws;
  u16* x_bf    = (u16*)(ws);                   // 128 MB  [65536][1024]
  u16* Kt      = (u16*)(ws + 134217728L);      // 128 MB  [b][h][s][d]
  u16* Vt      = (u16*)(ws + 268435456L);      // 128 MB  [b][h][d][s]
  u16* WT_attn = (u16*)(ws + 402653184L);      // 4 MB    [2048][1024]
  u16* WT_mlp  = (u16*)(ws + 406847488L);      // 2 MB
  u16* WT_proj = (u16*)(ws + 408944640L);      // 2 MB
  u16* q_ws    = (u16*)(ws + 412876800L);      // 2 MB    [b][h][64][64]
  u16* a_bf    = (u16*)(ws + 414973952L);      // 1.75 MB [896][1024]
  u16* maskT   = (u16*)(ws + 416808960L);      // 512 KB  [4096][64] bf16
  // attention partials REUSE the x_bf region (dead after gemm256<1>)
  float* partA = (float*)(ws);                 // 16 MB   [bh][chunk4][64q][64d]
  float* prs   = (float*)(ws + 16777216L);     // 256 KB  [bh][chunk4][64q]

  cast_f32_bf16<<<2048, 256, 0, stream>>>(x, x_bf, 16777216);
  transpose_all<<<dim3(32, 16, 4), 256, 0, stream>>>(W_attn, W_mlp, W_proj, mask,
                                                     WT_attn, WT_mlp, WT_proj, maskT);

  gemm256<0><<<1024, 512, 0, stream>>>(x_bf, WT_attn, b_attn, Kt);
  gemm256<1><<<dim3(64, 16), 512, 0, stream>>>(WT_attn + 1048576, x_bf, b_attn, Vt);
  gemm64<2><<<224, 256, 0, stream>>>(y, WT_mlp, b_mlp, q_ws);

  attn_part<<<dim3(256, 4), 256, 0, stream>>>(Kt, Vt, q_ws, maskT, partA, prs);
  attn_reduce<<<256, 256, 0, stream>>>(partA, prs, a_bf);

  gemm64<3><<<224, 256, 0, stream>>>(a_bf, WT_proj, b_proj, d_out);
}